// Round 1
// baseline (608.124 us; speedup 1.0000x reference)
//
#include <hip/hip_runtime.h>

// MS Deformable Attention 3D — fp32 reference-fidelity implementation.
// K1: value projection -> v_ws laid out [b][h][pix][d] (27.2 MB workspace)
// K2: per-8-query mega-kernel: q=query+pos, off/attn GEMMs, softmax,
//     bilinear gather from v_ws, output GEMM. Intermediates live in LDS.

#define EE   256
#define HH   8
#define DD   32
#define LL   4
#define PPk  8
#define NQq  10000
#define BSB  2
#define LENV 13294
#define MQ   8   // queries per block in K2, rows per block in K1

__global__ __launch_bounds__(256) void k_valproj(
    const float* __restrict__ value, const float* __restrict__ W_val,
    const float* __restrict__ b_val, float* __restrict__ v_ws) {
  __shared__ float sV[MQ][EE];
  const int tid = threadIdx.x;
  const int g0 = blockIdx.x * MQ;                 // row group over BSB*LENV
  const int total = BSB * LENV;
  for (int m = 0; m < MQ; ++m) {
    int g = g0 + m;
    if (g < total) sV[m][tid] = value[(long)g * EE + tid];
  }
  __syncthreads();
  float acc[MQ] = {};
  for (int k = 0; k < EE; ++k) {
    float wv = W_val[k * EE + tid];
#pragma unroll
    for (int m = 0; m < MQ; ++m) acc[m] += sV[m][k] * wv;
  }
  const float bv = b_val[tid];
  const int h = tid >> 5, c = tid & 31;
  for (int m = 0; m < MQ; ++m) {
    int g = g0 + m;
    if (g >= total) break;
    int b = g / LENV, pix = g % LENV;
    v_ws[(((long)b * HH + h) * LENV + pix) * DD + c] = acc[m] + bv;
  }
}

__global__ __launch_bounds__(256) void k_attn(
    const float* __restrict__ query, const float* __restrict__ query_pos,
    const float* __restrict__ refpts,
    const float* __restrict__ W_off, const float* __restrict__ b_off,
    const float* __restrict__ W_attn, const float* __restrict__ b_attn,
    const float* __restrict__ W_out, const float* __restrict__ b_out,
    const float* __restrict__ v_ws, float* __restrict__ out) {
  __shared__ float sQ[MQ][EE];        // q rows; reused as attn-output rows
  __shared__ float sW[MQ][256];       // attn logits -> softmaxed weights
  __shared__ float sX[MQ][256];       // sample x (pixel coords)
  __shared__ float sY[MQ][256];       // sample y
  const int tid = threadIdx.x;
  const int g0 = blockIdx.x * MQ;     // query group over BSB*NQq (no b-crossing)
  const int b = g0 / NQq;
  const int q0 = g0 % NQq;

  // ---- load q = query + query_pos ----
  for (int m = 0; m < MQ; ++m) {
    long idx = ((long)(b * NQq + q0 + m)) * EE + tid;
    sQ[m][tid] = query[idx] + query_pos[idx];
  }
  __syncthreads();

  // ---- offset (2 cols) + attn (1 col) logits per thread ----
  float accx[MQ] = {}, accy[MQ] = {}, acca[MQ] = {};
  for (int k = 0; k < EE; ++k) {
    float2 wo = *(const float2*)(W_off + (long)k * 512 + 2 * tid);
    float wa = W_attn[k * 256 + tid];
#pragma unroll
    for (int m = 0; m < MQ; ++m) {
      float qk = sQ[m][k];
      accx[m] += qk * wo.x;
      accy[m] += qk * wo.y;
      acca[m] += qk * wa;
    }
  }
  const float box = b_off[2 * tid], boy = b_off[2 * tid + 1], ba = b_attn[tid];

  // thread tid == sample s: h = s>>5, l = (s>>3)&3, p = s&7
  const int l = (tid >> 3) & 3;
  const float WsF[4] = {100.f, 50.f, 25.f, 13.f};
  const float HsF[4] = {100.f, 50.f, 25.f, 13.f};
  for (int m = 0; m < MQ; ++m) {
    long rbase = (((long)(b * NQq + q0 + m)) * LL + l) * 2;
    float rx = refpts[rbase + 0];
    float ry = refpts[rbase + 1];
    // x = (2*(rx + offx/Ws) - 1 + 1)*Ws/2 - 0.5 = rx*Ws + offx - 0.5
    sX[m][tid] = rx * WsF[l] + (accx[m] + box) - 0.5f;
    sY[m][tid] = ry * HsF[l] + (accy[m] + boy) - 0.5f;
    sW[m][tid] = acca[m] + ba;
  }
  __syncthreads();

  // ---- softmax over each (m, h) group of 32 ----
  if (tid < MQ * HH) {
    int m = tid >> 3, hh = tid & 7;
    float* ptr = &sW[m][hh * 32];
    float mx = ptr[0];
    for (int t = 1; t < 32; ++t) mx = fmaxf(mx, ptr[t]);
    float sum = 0.f;
    for (int t = 0; t < 32; ++t) { float e = __expf(ptr[t] - mx); ptr[t] = e; sum += e; }
    float inv = 1.f / sum;
    for (int t = 0; t < 32; ++t) ptr[t] *= inv;
  }
  __syncthreads();

  // ---- bilinear gather: thread = (h, channel c) ----
  const int h = tid >> 5, c = tid & 31;
  const int WsI[4] = {100, 50, 25, 13};
  const int HsI[4] = {100, 50, 25, 13};
  const int baseI[4] = {0, 10000, 12500, 13125};
  float oacc[MQ] = {};
  const float* vb = v_ws + ((long)b * HH + h) * (LENV * DD) + c;
  for (int i = 0; i < 32; ++i) {
    const int lvl = i >> 3;
    const int Wl = WsI[lvl], Hl = HsI[lvl];
    const float* vlb = vb + (long)baseI[lvl] * DD;
    const int s = h * 32 + i;
#pragma unroll
    for (int m = 0; m < MQ; ++m) {
      float x = sX[m][s], y = sY[m][s], w = sW[m][s];
      float fx0 = floorf(x), fy0 = floorf(y);
      int x0 = (int)fx0, y0 = (int)fy0;
      float fx = x - fx0, fy = y - fy0;
      float w00 = (1.f - fx) * (1.f - fy), w01 = fx * (1.f - fy);
      float w10 = (1.f - fx) * fy,        w11 = fx * fy;
      bool xv0 = (x0 >= 0) & (x0 < Wl);
      bool xv1 = (x0 + 1 >= 0) & (x0 + 1 < Wl);
      bool yv0 = (y0 >= 0) & (y0 < Hl);
      bool yv1 = (y0 + 1 >= 0) & (y0 + 1 < Hl);
      float v00 = 0.f, v01 = 0.f, v10 = 0.f, v11 = 0.f;
      if (yv0) {
        const float* r = vlb + (long)y0 * Wl * DD;
        if (xv0) v00 = r[(long)x0 * DD];
        if (xv1) v01 = r[(long)(x0 + 1) * DD];
      }
      if (yv1) {
        const float* r = vlb + (long)(y0 + 1) * Wl * DD;
        if (xv0) v10 = r[(long)x0 * DD];
        if (xv1) v11 = r[(long)(x0 + 1) * DD];
      }
      oacc[m] += w * (w00 * v00 + w01 * v01 + w10 * v10 + w11 * v11);
    }
  }
  __syncthreads();
  for (int m = 0; m < MQ; ++m) sQ[m][tid] = oacc[m];  // attn output, col = h*32+c = tid
  __syncthreads();

  // ---- output projection ----
  float facc[MQ] = {};
  for (int k = 0; k < EE; ++k) {
    float wo = W_out[k * EE + tid];
#pragma unroll
    for (int m = 0; m < MQ; ++m) facc[m] += sQ[m][k] * wo;
  }
  const float bo = b_out[tid];
  for (int m = 0; m < MQ; ++m) {
    out[((long)(b * NQq + q0 + m)) * EE + tid] = facc[m] + bo;
  }
}

extern "C" void kernel_launch(void* const* d_in, const int* in_sizes, int n_in,
                              void* d_out, int out_size, void* d_ws, size_t ws_size,
                              hipStream_t stream) {
  const float* query    = (const float*)d_in[0];
  const float* value    = (const float*)d_in[1];
  const float* query_pos= (const float*)d_in[2];
  const float* refpts   = (const float*)d_in[3];
  // d_in[4] spatial_shapes (int32) — compile-time constants, unused
  const float* W_off    = (const float*)d_in[5];
  const float* b_off    = (const float*)d_in[6];
  const float* W_attn   = (const float*)d_in[7];
  const float* b_attn   = (const float*)d_in[8];
  const float* W_val    = (const float*)d_in[9];
  const float* b_val    = (const float*)d_in[10];
  const float* W_out    = (const float*)d_in[11];
  const float* b_out    = (const float*)d_in[12];
  float* out  = (float*)d_out;
  float* v_ws = (float*)d_ws;   // BSB*HH*LENV*DD floats = 27.2 MB

  const int rows = BSB * LENV;
  dim3 blk(256);
  k_valproj<<<dim3((rows + MQ - 1) / MQ), blk, 0, stream>>>(value, W_val, b_val, v_ws);
  k_attn<<<dim3(BSB * NQq / MQ), blk, 0, stream>>>(
      query, query_pos, refpts, W_off, b_off, W_attn, b_attn,
      W_out, b_out, v_ws, out);
}

// Round 2
// 476.511 us; speedup vs baseline: 1.2762x; 1.2762x over previous
//
#include <hip/hip_runtime.h>

// MS Deformable Attention 3D — R2.
// K1: value projection (MQ_V=16 rows/block) -> v_ws [b][h][pix][d] fp32.
// K2: per-8-query block: q GEMMs (fp32 VALU), softmax, then PRECOMPUTED
//     16B/record sample table (bf16 premult corner weights + clamped packed
//     offsets) so the gather loop is branch-free and does no redundant
//     per-lane weight math.

#define EE   256
#define HH   8
#define DD   32
#define LL   4
#define NQq  10000
#define BSB  2
#define LENV 13294
#define MQ   8
#define MQV  16

__device__ __forceinline__ uint32_t bf16_of(float f) {
  uint32_t u = __float_as_uint(f);
  return (u + 0x7FFFu + ((u >> 16) & 1u)) >> 16;   // RNE
}

__global__ __launch_bounds__(256) void k_valproj(
    const float* __restrict__ value, const float* __restrict__ W_val,
    const float* __restrict__ b_val, float* __restrict__ v_ws) {
  __shared__ float sV[MQV][EE];
  const int tid = threadIdx.x;
  const int g0 = blockIdx.x * MQV;
  const int total = BSB * LENV;
#pragma unroll
  for (int m = 0; m < MQV; ++m) {
    int g = g0 + m;
    if (g < total) sV[m][tid] = value[(long)g * EE + tid];
  }
  __syncthreads();
  float acc[MQV] = {};
  for (int k = 0; k < EE; ++k) {
    float wv = W_val[k * EE + tid];
#pragma unroll
    for (int m = 0; m < MQV; ++m) acc[m] += sV[m][k] * wv;
  }
  const float bv = b_val[tid];
  const int h = tid >> 5, c = tid & 31;
#pragma unroll
  for (int m = 0; m < MQV; ++m) {
    int g = g0 + m;
    if (g >= total) break;
    int b = g / LENV, pix = g % LENV;
    v_ws[(((long)b * HH + h) * LENV + pix) * DD + c] = acc[m] + bv;
  }
}

__global__ __launch_bounds__(256) void k_attn(
    const float* __restrict__ query, const float* __restrict__ query_pos,
    const float* __restrict__ refpts,
    const float* __restrict__ W_off, const float* __restrict__ b_off,
    const float* __restrict__ W_attn, const float* __restrict__ b_attn,
    const float* __restrict__ W_out, const float* __restrict__ b_out,
    const float* __restrict__ v_ws, float* __restrict__ out) {
  __shared__ float sQ[MQ][EE];       // q -> logits/softmax -> attn-output
  __shared__ uint4 sTab[256][MQ];    // per (sample, m): packed gather record
  const int tid = threadIdx.x;
  const int g0 = blockIdx.x * MQ;
  const int b = g0 / NQq;
  const int q0 = g0 % NQq;

  // ---- q = query + query_pos ----
#pragma unroll
  for (int m = 0; m < MQ; ++m) {
    long idx = ((long)(b * NQq + q0 + m)) * EE + tid;
    sQ[m][tid] = query[idx] + query_pos[idx];
  }
  __syncthreads();

  // ---- GEMM1: per-thread = sample tid: offx, offy, attn logit ----
  float accx[MQ] = {}, accy[MQ] = {}, acca[MQ] = {};
  for (int k = 0; k < EE; ++k) {
    float2 wo = *(const float2*)(W_off + (long)k * 512 + 2 * tid);
    float wa = W_attn[k * 256 + tid];
#pragma unroll
    for (int m = 0; m < MQ; ++m) {
      float qk = sQ[m][k];
      accx[m] += qk * wo.x;
      accy[m] += qk * wo.y;
      acca[m] += qk * wa;
    }
  }
  const float box = b_off[2 * tid], boy = b_off[2 * tid + 1], ba = b_attn[tid];
  __syncthreads();                       // done reading sQ as q

  // ---- logits into sQ (aliased), softmax over each (m,h) group of 32 ----
#pragma unroll
  for (int m = 0; m < MQ; ++m) sQ[m][tid] = acca[m] + ba;
  __syncthreads();
  if (tid < MQ * HH) {
    int m = tid >> 3, hh = tid & 7;
    float* ptr = &sQ[m][hh * 32];
    float mx = ptr[0];
    for (int t = 1; t < 32; ++t) mx = fmaxf(mx, ptr[t]);
    float sum = 0.f;
    for (int t = 0; t < 32; ++t) { float e = __expf(ptr[t] - mx); ptr[t] = e; sum += e; }
    float inv = 1.f / sum;
    for (int t = 0; t < 32; ++t) ptr[t] *= inv;
  }
  __syncthreads();

  // ---- precompute packed gather records: thread tid = sample s ----
  {
    const int l = (tid >> 3) & 3;
    const int WlI[4] = {100, 50, 25, 13};
    const int HlI[4] = {100, 50, 25, 13};
    const int baseI[4] = {0, 10000, 12500, 13125};
    const float WlF[4] = {100.f, 50.f, 25.f, 13.f};
    const int Wl = WlI[l], Hl = HlI[l], base = baseI[l];
    const float WlFf = WlF[l], HlFf = WlF[l];
#pragma unroll
    for (int m = 0; m < MQ; ++m) {
      float w = sQ[m][tid];   // softmaxed attention weight
      float2 rp = *(const float2*)(refpts + (((long)(b * NQq + q0 + m)) * LL + l) * 2);
      float x = rp.x * WlFf + (accx[m] + box) - 0.5f;
      float y = rp.y * HlFf + (accy[m] + boy) - 0.5f;
      float fx0 = floorf(x), fy0 = floorf(y);
      int x0 = (int)fx0, y0 = (int)fy0;
      float fx = x - fx0, fy = y - fy0;
      bool xv0 = (x0 >= 0) & (x0 < Wl);
      bool xv1 = (x0 >= -1) & (x0 < Wl - 1);
      bool yv0 = (y0 >= 0) & (y0 < Hl);
      bool yv1 = (y0 >= -1) & (y0 < Hl - 1);
      float w00 = w * (1.f - fx) * (1.f - fy) * (float)(xv0 & yv0);
      float w01 = w * fx * (1.f - fy) * (float)(xv1 & yv0);
      float w10 = w * (1.f - fx) * fy * (float)(xv0 & yv1);
      float w11 = w * fx * fy * (float)(xv1 & yv1);
      int x0c = min(max(x0, 0), Wl - 1);
      int x1c = min(max(x0 + 1, 0), Wl - 1);
      int y0c = min(max(y0, 0), Hl - 1);
      int y1c = min(max(y0 + 1, 0), Hl - 1);
      uint32_t o00 = (uint32_t)(base + y0c * Wl + x0c) * 32u;
      uint32_t dx = (uint32_t)(x1c - x0c) * 32u;
      uint32_t dy = (uint32_t)(y1c - y0c) * (uint32_t)Wl * 32u;
      uint4 rec;
      rec.x = bf16_of(w00) | (bf16_of(w01) << 16);
      rec.y = bf16_of(w10) | (bf16_of(w11) << 16);
      rec.z = o00;
      rec.w = (dx << 16) | dy;
      sTab[tid][m] = rec;
    }
  }
  __syncthreads();

  // ---- gather: thread = (h, channel c); branch-free, table-driven ----
  const int h = tid >> 5, c = tid & 31;
  float oacc[MQ] = {};
  const float* vb = v_ws + ((long)b * HH + h) * ((long)LENV * DD) + c;
  for (int i = 0; i < 32; ++i) {
    const uint4* rec = &sTab[h * 32 + i][0];
#pragma unroll
    for (int m = 0; m < MQ; ++m) {
      uint4 r = rec[m];
      float w00 = __uint_as_float(r.x << 16);
      float w01 = __uint_as_float(r.x & 0xFFFF0000u);
      float w10 = __uint_as_float(r.y << 16);
      float w11 = __uint_as_float(r.y & 0xFFFF0000u);
      uint32_t dx = r.w >> 16, dy = r.w & 0xFFFFu;
      const float* p00 = vb + r.z;
      const float* p01 = p00 + dx;
      const float* p10 = p00 + dy;
      const float* p11 = p01 + dy;
      oacc[m] += w00 * p00[0] + w01 * p01[0] + w10 * p10[0] + w11 * p11[0];
    }
  }
  // sQ fully consumed before the table barrier — safe to overwrite
#pragma unroll
  for (int m = 0; m < MQ; ++m) sQ[m][tid] = oacc[m];
  __syncthreads();

  // ---- output projection ----
  float facc[MQ] = {};
  for (int k = 0; k < EE; ++k) {
    float wo = W_out[k * EE + tid];
#pragma unroll
    for (int m = 0; m < MQ; ++m) facc[m] += sQ[m][k] * wo;
  }
  const float bo = b_out[tid];
#pragma unroll
  for (int m = 0; m < MQ; ++m) {
    out[((long)(b * NQq + q0 + m)) * EE + tid] = facc[m] + bo;
  }
}

extern "C" void kernel_launch(void* const* d_in, const int* in_sizes, int n_in,
                              void* d_out, int out_size, void* d_ws, size_t ws_size,
                              hipStream_t stream) {
  const float* query    = (const float*)d_in[0];
  const float* value    = (const float*)d_in[1];
  const float* query_pos= (const float*)d_in[2];
  const float* refpts   = (const float*)d_in[3];
  const float* W_off    = (const float*)d_in[5];
  const float* b_off    = (const float*)d_in[6];
  const float* W_attn   = (const float*)d_in[7];
  const float* b_attn   = (const float*)d_in[8];
  const float* W_val    = (const float*)d_in[9];
  const float* b_val    = (const float*)d_in[10];
  const float* W_out    = (const float*)d_in[11];
  const float* b_out    = (const float*)d_in[12];
  float* out  = (float*)d_out;
  float* v_ws = (float*)d_ws;   // BSB*HH*LENV*DD floats = 27.2 MB

  const int rows = BSB * LENV;
  dim3 blk(256);
  k_valproj<<<dim3((rows + MQV - 1) / MQV), blk, 0, stream>>>(value, W_val, b_val, v_ws);
  k_attn<<<dim3(BSB * NQq / MQ), blk, 0, stream>>>(
      query, query_pos, refpts, W_off, b_off, W_attn, b_attn,
      W_out, b_out, v_ws, out);
}

// Round 3
// 265.714 us; speedup vs baseline: 2.2886x; 1.7933x over previous
//
#include <hip/hip_runtime.h>

// MS Deformable Attention 3D — R3: all GEMMs on MFMA (bf16), bf16 value
// tensor, conflict-free record table, branch-free table-driven gather.

#define EE   256
#define HH   8
#define LL   4
#define NQq  10000
#define BSB  2
#define LENV 13294
#define MQ   16
#define ROWS_V (BSB * LENV)   // 26588

typedef unsigned short u16;
typedef unsigned int   u32;
typedef __attribute__((ext_vector_type(8))) short bf16x8;
typedef __attribute__((ext_vector_type(4))) float f32x4;

__device__ __forceinline__ u32 bf16_of(float f) {
  u32 u = __float_as_uint(f);
  return (u + 0x7FFFu + ((u >> 16) & 1u)) >> 16;   // RNE
}
__device__ __forceinline__ float bf2f(u32 u) { return __uint_as_float(u << 16); }

__device__ __forceinline__ uint4 pack8(const float* f) {
  uint4 u;
  u.x = bf16_of(f[0]) | (bf16_of(f[1]) << 16);
  u.y = bf16_of(f[2]) | (bf16_of(f[3]) << 16);
  u.z = bf16_of(f[4]) | (bf16_of(f[5]) << 16);
  u.w = bf16_of(f[6]) | (bf16_of(f[7]) << 16);
  return u;
}

// ---- K0: weights -> bf16 B-fragment layout ----------------------------------
// frag element j of lane l, k-step s, n-tile t:  B[k = s*32+(l>>4)*8+j][n = t*16+(l&15)]
// stored at ((t*8+s)*64+l)*8 + j
__global__ __launch_bounds__(64) void k_prep(
    const float* __restrict__ W_off, const float* __restrict__ W_attn,
    const float* __restrict__ W_val, const float* __restrict__ W_out,
    u16* __restrict__ wcat, u16* __restrict__ wval, u16* __restrict__ wout) {
  const int tile = blockIdx.x >> 3, s = blockIdx.x & 7;
  const int l = threadIdx.x, quad = l >> 4, r16 = l & 15;
  float f[8];
  u16* dst;
  if (tile < 48) {            // concat(W_off[256x512], W_attn[256x256])
    int col = tile * 16 + r16;
#pragma unroll
    for (int j = 0; j < 8; ++j) {
      int k = s * 32 + quad * 8 + j;
      f[j] = (col < 512) ? W_off[k * 512 + col] : W_attn[k * 256 + (col - 512)];
    }
    dst = wcat + ((tile * 8 + s) * 64 + l) * 8;
  } else if (tile < 64) {     // W_val[256x256]
    int col = (tile - 48) * 16 + r16;
#pragma unroll
    for (int j = 0; j < 8; ++j) f[j] = W_val[(s * 32 + quad * 8 + j) * 256 + col];
    dst = wval + (((tile - 48) * 8 + s) * 64 + l) * 8;
  } else {                    // W_out[256x256]
    int col = (tile - 64) * 16 + r16;
#pragma unroll
    for (int j = 0; j < 8; ++j) f[j] = W_out[(s * 32 + quad * 8 + j) * 256 + col];
    dst = wout + (((tile - 64) * 8 + s) * 64 + l) * 8;
  }
  *(uint4*)dst = pack8(f);
}

// ---- K1: value projection, MFMA, 64 rows/block, bf16 output -----------------
__global__ __launch_bounds__(256) void k_valproj(
    const float* __restrict__ value, const float* __restrict__ b_val,
    const u16* __restrict__ wval, u16* __restrict__ v_ws) {
  __shared__ __align__(16) u16 sA[64][264];   // bf16 staged A; later aliased as result
  const int tid = threadIdx.x;
  const int g0 = blockIdx.x * 64;
#pragma unroll
  for (int ch = 0; ch < 8; ++ch) {
    int fidx = ch * 2048 + tid * 8;
    int row = fidx >> 8, col = fidx & 255;
    int g = g0 + row;
    float fv[8] = {0.f, 0.f, 0.f, 0.f, 0.f, 0.f, 0.f, 0.f};
    if (g < ROWS_V) {
      float4 a = *(const float4*)(value + (long)g * 256 + col);
      float4 b = *(const float4*)(value + (long)g * 256 + col + 4);
      fv[0] = a.x; fv[1] = a.y; fv[2] = a.z; fv[3] = a.w;
      fv[4] = b.x; fv[5] = b.y; fv[6] = b.z; fv[7] = b.w;
    }
    *(uint4*)&sA[row][col] = pack8(fv);
  }
  __syncthreads();
  const int wave = tid >> 6, lane = tid & 63, quad = lane >> 4, r16 = lane & 15;
  f32x4 acc[4][4] = {};
  for (int s = 0; s < 8; ++s) {
    bf16x8 af[4];
#pragma unroll
    for (int mt = 0; mt < 4; ++mt)
      af[mt] = *(const bf16x8*)&sA[mt * 16 + r16][s * 32 + quad * 8];
#pragma unroll
    for (int nt = 0; nt < 4; ++nt) {
      bf16x8 bfg = *(const bf16x8*)(wval + (((wave * 4 + nt) * 8 + s) * 64 + lane) * 8);
#pragma unroll
      for (int mt = 0; mt < 4; ++mt)
        acc[nt][mt] = __builtin_amdgcn_mfma_f32_16x16x32_bf16(af[mt], bfg, acc[nt][mt], 0, 0, 0);
    }
  }
  __syncthreads();
  // +bias, bf16, transpose-store into sA (dead) for coalesced global write
#pragma unroll
  for (int nt = 0; nt < 4; ++nt) {
    int col = (wave * 4 + nt) * 16 + r16;
    float bias = b_val[col];
#pragma unroll
    for (int mt = 0; mt < 4; ++mt)
#pragma unroll
      for (int rr = 0; rr < 4; ++rr)
        sA[mt * 16 + quad * 4 + rr][col] = (u16)bf16_of(acc[nt][mt][rr] + bias);
  }
  __syncthreads();
  const int h = tid >> 5, c = tid & 31;
  for (int r = 0; r < 64; ++r) {
    int g = g0 + r;
    if (g >= ROWS_V) break;
    int b = g / LENV, pix = g - b * LENV;
    v_ws[((b * 8 + h) * LENV + pix) * 32 + c] = sA[r][tid];
  }
}

// ---- K2: 16 queries/block, 512 threads: GEMM1 -> softmax -> records ->
//          gather -> out-proj --------------------------------------------------
__global__ __launch_bounds__(512, 4) void k_attn(
    const float* __restrict__ query, const float* __restrict__ query_pos,
    const float* __restrict__ refpts,
    const float* __restrict__ b_off, const float* __restrict__ b_attn,
    const float* __restrict__ b_out,
    const u16* __restrict__ wcat, const u16* __restrict__ wout,
    const u16* __restrict__ v_ws, float* __restrict__ out) {
  __shared__ __align__(16) char smem[65536];
  u16   (*sQ)[264]  = (u16(*)[264])smem;     // staged q (bf16)
  float (*sC)[772]  = (float(*)[772])smem;   // GEMM1 C (after sQ dead)
  uint4 (*sTab)[256] = (uint4(*)[256])smem;  // records [m][s] (after sC dead)
  u16   (*sO)[264]  = (u16(*)[264])smem;     // gather output (after sTab dead)

  const int tid = threadIdx.x;
  const int g0 = blockIdx.x * MQ;
  const int b = g0 / NQq;
  const int q0 = g0 - b * NQq;
  const int wave = tid >> 6, lane = tid & 63, quad = lane >> 4, r16 = lane & 15;

  // phase 0: stage q = query + query_pos as bf16
  {
    int fidx = tid * 8;
    int row = fidx >> 8, col = fidx & 255;
    long base = ((long)(b * NQq + q0 + row)) * 256 + col;
    float4 a0 = *(const float4*)(query + base);
    float4 a1 = *(const float4*)(query + base + 4);
    float4 p0 = *(const float4*)(query_pos + base);
    float4 p1 = *(const float4*)(query_pos + base + 4);
    float fv[8] = {a0.x + p0.x, a0.y + p0.y, a0.z + p0.z, a0.w + p0.w,
                   a1.x + p1.x, a1.y + p1.y, a1.z + p1.z, a1.w + p1.w};
    *(uint4*)&sQ[row][col] = pack8(fv);
  }
  __syncthreads();

  // phase 1: C[16][768] = q @ concat(W_off, W_attn)   (48 n-tiles / 8 waves)
  f32x4 acc[6] = {};
  for (int s = 0; s < 8; ++s) {
    bf16x8 af = *(const bf16x8*)&sQ[r16][s * 32 + quad * 8];
#pragma unroll
    for (int t6 = 0; t6 < 6; ++t6) {
      int tile = wave * 6 + t6;
      bf16x8 bfg = *(const bf16x8*)(wcat + ((tile * 8 + s) * 64 + lane) * 8);
      acc[t6] = __builtin_amdgcn_mfma_f32_16x16x32_bf16(af, bfg, acc[t6], 0, 0, 0);
    }
  }
  __syncthreads();                       // sQ dead
#pragma unroll
  for (int t6 = 0; t6 < 6; ++t6) {
    int col = (wave * 6 + t6) * 16 + r16;
#pragma unroll
    for (int rr = 0; rr < 4; ++rr)
      sC[quad * 4 + rr][col] = acc[t6][rr];
  }
  __syncthreads();

  // phase 2: softmax per (m, h) over 32 logits (cols 512..767), bias folded
  if (tid < MQ * HH) {
    int m = tid >> 3, h = tid & 7;
    float* p = &sC[m][512 + h * 32];
    const float* ba = b_attn + h * 32;
    float mx = -1e30f;
    for (int j = 0; j < 32; ++j) { float v = p[j] + ba[j]; p[j] = v; mx = fmaxf(mx, v); }
    float sum = 0.f;
    for (int j = 0; j < 32; ++j) { float e = __expf(p[j] - mx); p[j] = e; sum += e; }
    float inv = 1.f / sum;
    for (int j = 0; j < 32; ++j) p[j] *= inv;
  }
  __syncthreads();

  // phase 3: build packed records (regs bridge sC -> sTab alias)
  uint4 recs[8];
  {
    const int s = tid & 255, mh = tid >> 8;
    const int l = (s >> 3) & 3;
    const int WlI[4] = {100, 50, 25, 13};
    const int baseI[4] = {0, 10000, 12500, 13125};
    const int Wl = WlI[l], Hl = WlI[l], base = baseI[l];
    const float WlF = (float)Wl;
    const float box = b_off[2 * s], boy = b_off[2 * s + 1];
#pragma unroll
    for (int mm = 0; mm < 8; ++mm) {
      int m = mh * 8 + mm;
      float w = sC[m][512 + s];
      float ax = sC[m][2 * s], ay = sC[m][2 * s + 1];
      float2 rp = *(const float2*)(refpts + (((long)(b * NQq + q0 + m)) * LL + l) * 2);
      float x = rp.x * WlF + (ax + box) - 0.5f;
      float y = rp.y * WlF + (ay + boy) - 0.5f;
      float fx0 = floorf(x), fy0 = floorf(y);
      int x0 = (int)fx0, y0 = (int)fy0;
      float fx = x - fx0, fy = y - fy0;
      bool xv0 = (x0 >= 0) & (x0 < Wl);
      bool xv1 = (x0 >= -1) & (x0 < Wl - 1);
      bool yv0 = (y0 >= 0) & (y0 < Hl);
      bool yv1 = (y0 >= -1) & (y0 < Hl - 1);
      float w00 = w * (1.f - fx) * (1.f - fy) * (float)(xv0 & yv0);
      float w01 = w * fx * (1.f - fy) * (float)(xv1 & yv0);
      float w10 = w * (1.f - fx) * fy * (float)(xv0 & yv1);
      float w11 = w * fx * fy * (float)(xv1 & yv1);
      int x0c = min(max(x0, 0), Wl - 1);
      int x1c = min(max(x0 + 1, 0), Wl - 1);
      int y0c = min(max(y0, 0), Hl - 1);
      int y1c = min(max(y0 + 1, 0), Hl - 1);
      u32 o00 = (u32)(base + y0c * Wl + x0c) * 32u;
      u32 dx = (u32)(x1c - x0c) * 32u;
      u32 dy = (u32)(y1c - y0c) * (u32)Wl * 32u;
      uint4 rec;
      rec.x = bf16_of(w00) | (bf16_of(w01) << 16);
      rec.y = bf16_of(w10) | (bf16_of(w11) << 16);
      rec.z = o00;
      rec.w = (dx << 16) | dy;
      recs[mm] = rec;
    }
  }
  __syncthreads();                       // sC dead
  {
    const int s = tid & 255, mh = tid >> 8;
#pragma unroll
    for (int mm = 0; mm < 8; ++mm) sTab[mh * 8 + mm][s] = recs[mm];
  }
  __syncthreads();

  // phase 4: gather (thread = (m-half, h, channel)); bf16 v, 32-bit offsets
  const int half = tid >> 8, h = (tid >> 5) & 7, c = tid & 31;
  float oacc[8] = {};
  {
    const u32 hcb = ((u32)(b * 8 + h) * (u32)LENV) * 32u + (u32)c;
    for (int i = 0; i < 32; ++i) {
      int srow = h * 32 + i;
#pragma unroll
      for (int mm = 0; mm < 8; ++mm) {
        uint4 r = sTab[half * 8 + mm][srow];
        float w00 = __uint_as_float(r.x << 16);
        float w01 = __uint_as_float(r.x & 0xFFFF0000u);
        float w10 = __uint_as_float(r.y << 16);
        float w11 = __uint_as_float(r.y & 0xFFFF0000u);
        u32 dx = r.w >> 16, dy = r.w & 0xFFFFu;
        u32 o00 = hcb + r.z;
        float v00 = bf2f((u32)v_ws[o00]);
        float v01 = bf2f((u32)v_ws[o00 + dx]);
        float v10 = bf2f((u32)v_ws[o00 + dy]);
        float v11 = bf2f((u32)v_ws[o00 + dx + dy]);
        oacc[mm] += w00 * v00 + w01 * v01 + w10 * v10 + w11 * v11;
      }
    }
  }
  __syncthreads();                       // sTab dead
#pragma unroll
  for (int mm = 0; mm < 8; ++mm)
    sO[half * 8 + mm][h * 32 + c] = (u16)bf16_of(oacc[mm]);
  __syncthreads();

  // phase 5: out = gathered @ W_out + b_out  (16 n-tiles / 8 waves)
  f32x4 acc2[2] = {};
  for (int s = 0; s < 8; ++s) {
    bf16x8 af = *(const bf16x8*)&sO[r16][s * 32 + quad * 8];
#pragma unroll
    for (int t2 = 0; t2 < 2; ++t2) {
      int tile = wave * 2 + t2;
      bf16x8 bfg = *(const bf16x8*)(wout + ((tile * 8 + s) * 64 + lane) * 8);
      acc2[t2] = __builtin_amdgcn_mfma_f32_16x16x32_bf16(af, bfg, acc2[t2], 0, 0, 0);
    }
  }
#pragma unroll
  for (int t2 = 0; t2 < 2; ++t2) {
    int col = (wave * 2 + t2) * 16 + r16;
    float bias = b_out[col];
#pragma unroll
    for (int rr = 0; rr < 4; ++rr) {
      int row = quad * 4 + rr;
      out[((long)(b * NQq + q0 + row)) * 256 + col] = acc2[t2][rr] + bias;
    }
  }
}

extern "C" void kernel_launch(void* const* d_in, const int* in_sizes, int n_in,
                              void* d_out, int out_size, void* d_ws, size_t ws_size,
                              hipStream_t stream) {
  const float* query     = (const float*)d_in[0];
  const float* value     = (const float*)d_in[1];
  const float* query_pos = (const float*)d_in[2];
  const float* refpts    = (const float*)d_in[3];
  const float* W_off     = (const float*)d_in[5];
  const float* b_off     = (const float*)d_in[6];
  const float* W_attn    = (const float*)d_in[7];
  const float* b_attn    = (const float*)d_in[8];
  const float* W_val     = (const float*)d_in[9];
  const float* b_val     = (const float*)d_in[10];
  const float* W_out     = (const float*)d_in[11];
  const float* b_out     = (const float*)d_in[12];
  float* out = (float*)d_out;

  char* ws = (char*)d_ws;
  u16* v_ws = (u16*)ws;                                   // 13,613,056 B
  u16* wcat = (u16*)(ws + 13613056);                      //    393,216 B
  u16* wval = (u16*)(ws + 13613056 + 393216);             //    131,072 B
  u16* wout = (u16*)(ws + 13613056 + 393216 + 131072);    //    131,072 B

  k_prep<<<dim3(80 * 8), dim3(64), 0, stream>>>(W_off, W_attn, W_val, W_out,
                                                wcat, wval, wout);
  k_valproj<<<dim3((ROWS_V + 63) / 64), dim3(256), 0, stream>>>(value, b_val, wval, v_ws);
  k_attn<<<dim3(BSB * NQq / MQ), dim3(512), 0, stream>>>(
      query, query_pos, refpts, b_off, b_attn, b_out, wcat, wout, v_ws, out);
}